// Round 1
// baseline (2063.149 us; speedup 1.0000x reference)
//
#include <hip/hip_runtime.h>
#include <hip/hip_bf16.h>
#include <stdint.h>

#define BB 64
#define TT 32
#define HID 512
#define XD  512
#define NV  10000

typedef __bf16 bf16x8 __attribute__((ext_vector_type(8)));
typedef float  f32x4  __attribute__((ext_vector_type(4)));

__device__ inline void split2(float w, __bf16& hi, __bf16& lo) {
  hi = (__bf16)w;
  lo = (__bf16)(w - (float)hi);
}

__device__ inline unsigned long long shflxor64(unsigned long long v, int m) {
  unsigned lo = (unsigned)(v & 0xFFFFFFFFull);
  unsigned hi = (unsigned)(v >> 32);
  lo = __shfl_xor(lo, m);
  hi = __shfl_xor(hi, m);
  return ((unsigned long long)hi << 32) | lo;
}

// monotonic packing of (logit, vocab index); larger u64 = larger logit,
// ties broken toward SMALLER index (matches jnp.argmax first-occurrence).
__device__ inline unsigned long long packkey(float f, int v) {
  unsigned ub = __float_as_uint(f);
  unsigned key = (ub & 0x80000000u) ? ~ub : (ub | 0x80000000u);
  return ((unsigned long long)key << 32) | (unsigned)(0xFFFFFFFFu - (unsigned)v);
}

__global__ __launch_bounds__(256) void k_init(const float* __restrict__ h0,
                                              const float* __restrict__ c0,
                                              __bf16* __restrict__ h_hi,
                                              __bf16* __restrict__ h_lo,
                                              float* __restrict__ c_ws) {
  int i = blockIdx.x * 256 + threadIdx.x;   // grid is exactly BB*HID/256
  float h = h0[i];
  __bf16 hi, lo; split2(h, hi, lo);
  h_hi[i] = hi; h_lo[i] = lo;
  c_ws[i] = c0[i];
}

// blocks 0..127: LSTM cell for step t (block b owns hidden cols [4b,4b+4) of all 4 gates)
// blocks 128..191: normalize softmax row of step t-1 (block 128+r handles batch row r)
__global__ __launch_bounds__(256) void k_cell(
    int t,
    const float* __restrict__ x, const float* __restrict__ emb,
    const float* __restrict__ Whi, const float* __restrict__ Whf,
    const float* __restrict__ Who, const float* __restrict__ Whz,
    const float* __restrict__ Wxi, const float* __restrict__ Wxf,
    const float* __restrict__ Wxo, const float* __restrict__ Wxz,
    const float* __restrict__ bi, const float* __restrict__ bf_,
    const float* __restrict__ bo, const float* __restrict__ bz,
    const __bf16* __restrict__ h_r_hi, const __bf16* __restrict__ h_r_lo,
    __bf16* __restrict__ h_w_hi, __bf16* __restrict__ h_w_lo,
    float* __restrict__ c_ws, float* __restrict__ out,
    const unsigned long long* __restrict__ gmax_prev,
    const float* __restrict__ gsum_prev,
    unsigned long long* __restrict__ gmax_cur,
    float* __restrict__ gsum_cur)
{
  int bid = blockIdx.x;
  int tid = threadIdx.x;

  if (bid >= 128) {                  // ---- normalize y[t-1] ----
    if (t == 0) return;
    int r = bid - 128;
    float inv = 1.0f / gsum_prev[r];
    float* yrow = out + (size_t)r * TT * NV + (size_t)(t - 1) * NV;
    for (int v = tid; v < NV; v += 256) yrow[v] *= inv;
    return;
  }
  if (t >= TT) return;               // t==TT launch only normalizes

  if (bid == 0 && tid < 64) {        // zero this step's reduction buffers
    gsum_cur[tid] = 0.0f;
    gmax_cur[tid] = 0ULL;
  }

  const int KC = 128;
  __shared__ __bf16 Bh[16][KC + 8];
  __shared__ __bf16 Bl[16][KC + 8];
  __shared__ float  pre[64][17];

  int lane = tid & 63, wid = tid >> 6;
  int n0 = bid * 4;                  // 4 hidden cols per gate for this block
  int row = wid * 16 + (lane & 15);  // batch row for this lane's A fragments

  const float* xrow;
  if (t == 0) {
    xrow = x + (size_t)row * TT * XD;            // x[row][0][:]
  } else {
    unsigned long long mk = gmax_prev[row];
    int tok = (int)(0xFFFFFFFFu - (unsigned)(mk & 0xFFFFFFFFull));
    xrow = emb + (size_t)tok * XD;
  }

  const float* WH[4] = {Whi, Whf, Who, Whz};
  const float* WX[4] = {Wxi, Wxf, Wxo, Wxz};

  f32x4 accA = {0.f, 0.f, 0.f, 0.f};
  f32x4 accB = {0.f, 0.f, 0.f, 0.f};

  for (int k0 = 0; k0 < 2 * HID; k0 += KC) {
    bool isH = (k0 < HID);
    __syncthreads();
    // stage KC x 16 fp32 weights -> hi/lo bf16 LDS tiles (transposed: [col][k])
    #pragma unroll
    for (int i2 = 0; i2 < 2; i2++) {
      int e = tid + i2 * 256;          // 0..511 ; e = k*4 + g
      int k = e >> 2, g = e & 3;
      const float* src = isH ? (WH[g] + (size_t)(k0 + k) * HID + n0)
                             : (WX[g] + (size_t)(k0 + k - HID) * HID + n0);
      float4 w = *(const float4*)src;
      #pragma unroll
      for (int j = 0; j < 4; j++) {
        float wv = ((const float*)&w)[j];
        __bf16 hi, lo; split2(wv, hi, lo);
        Bh[g * 4 + j][k] = hi;
        Bl[g * 4 + j][k] = lo;
      }
    }
    __syncthreads();

    #pragma unroll
    for (int ks = 0; ks < KC / 32; ks++) {
      int kk = k0 + ks * 32 + (lane >> 4) * 8;
      bf16x8 ah, al;
      if (isH) {
        ah = *(const bf16x8*)(h_r_hi + (size_t)row * HID + kk);
        al = *(const bf16x8*)(h_r_lo + (size_t)row * HID + kk);
      } else {
        const float* xp = xrow + (kk - HID);
        float4 w0 = *(const float4*)(xp);
        float4 w1 = *(const float4*)(xp + 4);
        #pragma unroll
        for (int j = 0; j < 4; j++) {
          __bf16 hi, lo;
          split2(((const float*)&w0)[j], hi, lo); ah[j] = hi; al[j] = lo;
          split2(((const float*)&w1)[j], hi, lo); ah[4 + j] = hi; al[4 + j] = lo;
        }
      }
      int kl = ks * 32 + (lane >> 4) * 8;
      bf16x8 bh = *(const bf16x8*)&Bh[lane & 15][kl];
      bf16x8 bl = *(const bf16x8*)&Bl[lane & 15][kl];
      accA = __builtin_amdgcn_mfma_f32_16x16x32_bf16(ah, bh, accA, 0, 0, 0);
      accB = __builtin_amdgcn_mfma_f32_16x16x32_bf16(ah, bl, accB, 0, 0, 0);
      accB = __builtin_amdgcn_mfma_f32_16x16x32_bf16(al, bh, accB, 0, 0, 0);
      accA = __builtin_amdgcn_mfma_f32_16x16x32_bf16(al, bl, accA, 0, 0, 0);
    }
  }

  __syncthreads();
  #pragma unroll
  for (int j = 0; j < 4; j++)
    pre[wid * 16 + (lane >> 4) * 4 + j][lane & 15] = accA[j] + accB[j];
  __syncthreads();

  {
    int rloc = tid >> 2, q = tid & 3;
    int n = n0 + q;
    float pi = pre[rloc][q]      + bi[n];
    float pf = pre[rloc][4 + q]  + bf_[n];
    float po = pre[rloc][8 + q]  + bo[n];
    float pz = pre[rloc][12 + q] + bz[n];
    float ig = 1.f / (1.f + expf(-pi));
    float fg = 1.f / (1.f + expf(-pf));
    float og = 1.f / (1.f + expf(-po));
    float zg = tanhf(pz);
    float cp = c_ws[rloc * HID + n];
    float cn = ig * zg + fg * cp;
    c_ws[rloc * HID + n] = cn;
    out[(size_t)BB * TT * NV + (size_t)rloc * TT * HID + (size_t)t * HID + n] = cn;
    float hn = og * tanhf(cn);
    __bf16 hh, hl; split2(hn, hh, hl);
    h_w_hi[rloc * HID + n] = hh;
    h_w_lo[rloc * HID + n] = hl;
  }
}

// 209 blocks x 48 vocab cols: logits + exp + per-row sum/argmax partials
__global__ __launch_bounds__(256) void k_logits(
    int t, int lidx,
    const float* __restrict__ W_lin, const float* __restrict__ b_lin,
    const __bf16* __restrict__ hhi, const __bf16* __restrict__ hlo,
    float* __restrict__ out,
    unsigned long long* __restrict__ gmax_cur, float* __restrict__ gsum_cur)
{
  const int VB = 48, KC = 128;
  int tid = threadIdx.x;
  int lane = tid & 63, wid = tid >> 6;
  int v0 = blockIdx.x * VB;
  const float* W = W_lin + (size_t)lidx * HID * NV;

  __shared__ __bf16 Bh[VB][KC + 8];
  __shared__ __bf16 Bl[VB][KC + 8];

  f32x4 acc[3][2] = {};

  for (int k0 = 0; k0 < HID; k0 += KC) {
    __syncthreads();
    #pragma unroll
    for (int i2 = 0; i2 < 6; i2++) {
      int e = tid + i2 * 256;            // 0..1535 ; e = k*12 + p
      int k = e / 12, p = e % 12;
      // note: reads past v=9999 stay inside W_lin array (lidx<=30), masked later
      float4 w = *(const float4*)(W + (size_t)(k0 + k) * NV + v0 + p * 4);
      #pragma unroll
      for (int j = 0; j < 4; j++) {
        float wv = ((const float*)&w)[j];
        __bf16 hi, lo; split2(wv, hi, lo);
        Bh[p * 4 + j][k] = hi;
        Bl[p * 4 + j][k] = lo;
      }
    }
    __syncthreads();

    int row = wid * 16 + (lane & 15);
    #pragma unroll
    for (int ks = 0; ks < KC / 32; ks++) {
      int kk = k0 + ks * 32 + (lane >> 4) * 8;
      bf16x8 ah = *(const bf16x8*)(hhi + (size_t)row * HID + kk);
      bf16x8 al = *(const bf16x8*)(hlo + (size_t)row * HID + kk);
      int kl = ks * 32 + (lane >> 4) * 8;
      #pragma unroll
      for (int vt = 0; vt < 3; vt++) {
        bf16x8 bh = *(const bf16x8*)&Bh[vt * 16 + (lane & 15)][kl];
        bf16x8 bl = *(const bf16x8*)&Bl[vt * 16 + (lane & 15)][kl];
        acc[vt][0] = __builtin_amdgcn_mfma_f32_16x16x32_bf16(ah, bh, acc[vt][0], 0, 0, 0);
        acc[vt][1] = __builtin_amdgcn_mfma_f32_16x16x32_bf16(ah, bl, acc[vt][1], 0, 0, 0);
        acc[vt][1] = __builtin_amdgcn_mfma_f32_16x16x32_bf16(al, bh, acc[vt][1], 0, 0, 0);
        acc[vt][0] = __builtin_amdgcn_mfma_f32_16x16x32_bf16(al, bl, acc[vt][0], 0, 0, 0);
      }
    }
  }

  const float* brow = b_lin + (size_t)lidx * NV;
  float rsum[4] = {0.f, 0.f, 0.f, 0.f};
  unsigned long long rmax[4] = {0ULL, 0ULL, 0ULL, 0ULL};

  #pragma unroll
  for (int vt = 0; vt < 3; vt++) {
    int v = v0 + vt * 16 + (lane & 15);
    if (v < NV) {
      float bb = brow[v];
      #pragma unroll
      for (int j = 0; j < 4; j++) {
        int r = wid * 16 + (lane >> 4) * 4 + j;
        float logit = acc[vt][0][j] + acc[vt][1][j] + bb;
        float e = expf(logit);        // no max-subtract: |logit| <= ~10
        out[(size_t)r * TT * NV + (size_t)t * NV + v] = e;
        rsum[j] += e;
        unsigned long long pk = packkey(logit, v);
        if (pk > rmax[j]) rmax[j] = pk;
      }
    }
  }

  #pragma unroll
  for (int off = 1; off < 16; off <<= 1) {
    #pragma unroll
    for (int j = 0; j < 4; j++) {
      rsum[j] += __shfl_xor(rsum[j], off);
      unsigned long long o = shflxor64(rmax[j], off);
      if (o > rmax[j]) rmax[j] = o;
    }
  }
  if ((lane & 15) == 0) {
    #pragma unroll
    for (int j = 0; j < 4; j++) {
      int r = wid * 16 + (lane >> 4) * 4 + j;
      atomicAdd(&gsum_cur[r], rsum[j]);
      atomicMax(&gmax_cur[r], rmax[j]);
    }
  }
}

extern "C" void kernel_launch(void* const* d_in, const int* in_sizes, int n_in,
                              void* d_out, int out_size, void* d_ws, size_t ws_size,
                              hipStream_t stream) {
  const float* x     = (const float*)d_in[0];
  const float* h0    = (const float*)d_in[1];
  const float* c0    = (const float*)d_in[2];
  const float* W_hi  = (const float*)d_in[3];
  const float* W_xi  = (const float*)d_in[4];
  const float* b_i   = (const float*)d_in[5];
  const float* W_hf  = (const float*)d_in[6];
  const float* W_xf  = (const float*)d_in[7];
  const float* b_f   = (const float*)d_in[8];
  const float* W_ho  = (const float*)d_in[9];
  const float* W_xo  = (const float*)d_in[10];
  const float* b_o   = (const float*)d_in[11];
  const float* W_hz  = (const float*)d_in[12];
  const float* W_xz  = (const float*)d_in[13];
  const float* b_z   = (const float*)d_in[14];
  const float* W_lin = (const float*)d_in[15];
  const float* b_lin = (const float*)d_in[16];
  const float* emb   = (const float*)d_in[17];

  float* out = (float*)d_out;
  char* ws = (char*)d_ws;
  __bf16* h_hi = (__bf16*)ws;                                   // [2][64][512]
  __bf16* h_lo = (__bf16*)(ws + 131072);                        // [2][64][512]
  float*  c_ws = (float*)(ws + 262144);                         // [64][512]
  unsigned long long* gmax = (unsigned long long*)(ws + 393216);// [2][64]
  float*  gsum = (float*)(ws + 394240);                         // [2][64]

  k_init<<<128, 256, 0, stream>>>(h0, c0, h_hi, h_lo, c_ws);

  for (int t = 0; t <= TT; t++) {
    __bf16* hr  = h_hi + (size_t)(t & 1) * BB * HID;
    __bf16* hrl = h_lo + (size_t)(t & 1) * BB * HID;
    __bf16* hw  = h_hi + (size_t)((t + 1) & 1) * BB * HID;
    __bf16* hwl = h_lo + (size_t)((t + 1) & 1) * BB * HID;
    unsigned long long* gmax_prev = gmax + ((t + 1) & 1) * BB;  // (t-1)&1 == (t+1)&1
    float*  gsum_prev = gsum + ((t + 1) & 1) * BB;
    unsigned long long* gmax_cur  = gmax + (t & 1) * BB;
    float*  gsum_cur  = gsum + (t & 1) * BB;

    k_cell<<<192, 256, 0, stream>>>(t, x, emb,
        W_hi, W_hf, W_ho, W_hz, W_xi, W_xf, W_xo, W_xz,
        b_i, b_f, b_o, b_z,
        hr, hrl, hw, hwl, c_ws, out,
        gmax_prev, gsum_prev, gmax_cur, gsum_cur);

    if (t < TT) {
      int lidx = (t == 0) ? 0 : t - 1;
      k_logits<<<209, 256, 0, stream>>>(t, lidx, W_lin, b_lin,
                                        hw, hwl, out, gmax_cur, gsum_cur);
    }
  }
}